// Round 9
// baseline (646.605 us; speedup 1.0000x reference)
//
#include <hip/hip_runtime.h>
#include <cstdint>
#include <cstddef>

#define NNODES 50000
#define TT 24
#define DYNF 16
#define STATF 8
#define HDIM 64
#define NEDGES 1600000
#define NB 16   // nodes per GRU block

typedef __attribute__((ext_vector_type(8))) short bf16x8;
typedef __attribute__((ext_vector_type(4))) float f32x4;

// fp32 -> bf16 with round-to-nearest-even
__device__ __forceinline__ unsigned short f2bf(float f) {
    unsigned u = __float_as_uint(f);
    u = (u + 0x7FFFu + ((u >> 16) & 1u)) >> 16;
    return (unsigned short)u;
}
__device__ __forceinline__ float bf2f(unsigned short s) {
    return __uint_as_float((unsigned)s << 16);
}
__device__ __forceinline__ bf16x8 cvt8(const float* __restrict__ p) {
    bf16x8 r;
    #pragma unroll
    for (int i = 0; i < 8; ++i) r[i] = (short)f2bf(p[i]);
    return r;
}
__device__ __forceinline__ bf16x8 zero8() {
    bf16x8 z;
    #pragma unroll
    for (int i = 0; i < 8; ++i) z[i] = 0;
    return z;
}
// robust fast tanh: no inf/inf NaN at extremes
__device__ __forceinline__ float fast_tanh(float x) {
    float e = __expf(2.f * x);
    return 1.f - 2.f * __builtin_amdgcn_rcpf(e + 1.f);
}

// ---------------------------------------------------------------------------
// MFMA GRU + fused W1 transform. Block = 16 nodes x 4 waves -> grid 3125,
// up to 8 blocks/CU (32 waves/CU) co-resident: hides per-step latency chain.
// Per step: G(16x192) = [h|x_t](16x96) @ B(96x192), 16x16x32 bf16 MFMA.
// Wave w owns gate N-tiles {w, w+4, w+8}; C/D: col=gate-feature, row=node.
// Sigmoid pair shares one rcp: q=rcp(dr*dz); R=q*dz; Z=q*dr (5 transc/elem).
// ---------------------------------------------------------------------------
__global__ __launch_bounds__(256, 8) void gru_w1_kernel(
    const float* __restrict__ x_dyn, const float* __restrict__ x_stat,
    const float* __restrict__ Wih, const float* __restrict__ Whh,
    const float* __restrict__ bih, const float* __restrict__ bhh,
    const float* __restrict__ W1, unsigned short* __restrict__ t1)
{
    constexpr int S_H = 72;   // bf16 units per hbuf row (144B: 16B-aligned)
    constexpr int S_X = 40;   // bf16 units per xbuf row
    __shared__ short hbuf[2][NB * S_H];   // [node][feature] bf16, dbuf
    __shared__ short xbuf[2][NB * S_X];   // [node][k] bf16; k 16..31 zeroed

    const int tid = (int)threadIdx.x;
    const int lane = tid & 63;
    const int w = __builtin_amdgcn_readfirstlane(tid >> 6);  // wave 0..3
    const int col = lane & 15;
    const int quad = lane >> 4;
    const int node0 = (int)blockIdx.x * NB;

    bf16x8 Bh[3][2];
    bf16x8 Bx[3];
    #pragma unroll
    for (int g = 0; g < 3; ++g) {
        const int n = (w + g * 4) * 16 + col;   // gate row in [0,192)
        #pragma unroll
        for (int kt = 0; kt < 2; ++kt)
            Bh[g][kt] = cvt8(Whh + (size_t)n * HDIM + kt * 32 + quad * 8);
        Bx[g] = (quad < 2) ? cvt8(Wih + (size_t)n * DYNF + quad * 8) : zero8();
    }

    const int jg = w * 16 + col;                 // feature 0..63
    const float b_r  = bih[jg]        + bhh[jg];
    const float b_z  = bih[HDIM + jg] + bhh[HDIM + jg];
    const float b_xn = bih[2 * HDIM + jg];
    const float b_hn = bhh[2 * HDIM + jg];

    for (int i = tid; i < NB * S_H; i += 256) hbuf[0][i] = 0;

    // stage x_t: 16 nodes x 16 features = 256 tasks, 1 elem each
    auto stage_x = [&](int t, int b) {
        const int nd = tid >> 4, c = tid & 15;
        int node = node0 + nd;
        if (node >= NNODES) node = 0;
        const float v = x_dyn[(size_t)node * (TT * DYNF) + t * DYNF + c];
        xbuf[b][nd * S_X + c] = (short)f2bf(v);
        xbuf[b][nd * S_X + 16 + c] = 0;
    };
    stage_x(0, 0);

    float hprev[4];
    #pragma unroll
    for (int r = 0; r < 4; ++r) hprev[r] = 0.f;

    for (int t = 0; t < TT; ++t) {
        const int rb = t & 1;
        __syncthreads();   // hbuf[rb], xbuf[rb] ready

        const bf16x8 a0 = *reinterpret_cast<const bf16x8*>(&hbuf[rb][col * S_H + quad * 8]);
        const bf16x8 a1 = *reinterpret_cast<const bf16x8*>(&hbuf[rb][col * S_H + 32 + quad * 8]);
        const bf16x8 ax = *reinterpret_cast<const bf16x8*>(&xbuf[rb][col * S_X + quad * 8]);
        const f32x4 z4 = {0.f, 0.f, 0.f, 0.f};
        f32x4 accr, accz, accnh, accnx;
        accr  = __builtin_amdgcn_mfma_f32_16x16x32_bf16(a0, Bh[0][0], z4, 0, 0, 0);
        accr  = __builtin_amdgcn_mfma_f32_16x16x32_bf16(a1, Bh[0][1], accr, 0, 0, 0);
        accr  = __builtin_amdgcn_mfma_f32_16x16x32_bf16(ax, Bx[0],    accr, 0, 0, 0);
        accz  = __builtin_amdgcn_mfma_f32_16x16x32_bf16(a0, Bh[1][0], z4, 0, 0, 0);
        accz  = __builtin_amdgcn_mfma_f32_16x16x32_bf16(a1, Bh[1][1], accz, 0, 0, 0);
        accz  = __builtin_amdgcn_mfma_f32_16x16x32_bf16(ax, Bx[1],    accz, 0, 0, 0);
        accnh = __builtin_amdgcn_mfma_f32_16x16x32_bf16(a0, Bh[2][0], z4, 0, 0, 0);
        accnh = __builtin_amdgcn_mfma_f32_16x16x32_bf16(a1, Bh[2][1], accnh, 0, 0, 0);
        accnx = __builtin_amdgcn_mfma_f32_16x16x32_bf16(ax, Bx[2],    z4, 0, 0, 0);

        if (t + 1 < TT) stage_x(t + 1, rb ^ 1);  // overlap with MFMA drain

        #pragma unroll
        for (int r = 0; r < 4; ++r) {
            const float dr = 1.f + __expf(-(accr[r] + b_r));
            const float dz = 1.f + __expf(-(accz[r] + b_z));
            const float q  = __builtin_amdgcn_rcpf(dr * dz);
            const float R  = q * dz;           // = 1/dr
            const float Z  = q * dr;           // = 1/dz
            const float Nn = fast_tanh(accnx[r] + b_xn + R * (accnh[r] + b_hn));
            const float hn = Nn + Z * (hprev[r] - Nn);
            hprev[r] = hn;
            hbuf[rb ^ 1][(quad * 4 + r) * S_H + jg] = (short)f2bf(hn);
        }
    }
    __syncthreads();   // final h in hbuf[0]

    // ---- fused W1: t1 = [h | x_stat] @ W1 (bf16 out) ----
    bf16x8 Bw0, Bw1, Bw2;
    #pragma unroll
    for (int j = 0; j < 8; ++j) {
        Bw0[j] = (short)f2bf(W1[(size_t)(quad * 8 + j) * HDIM + jg]);
        Bw1[j] = (short)f2bf(W1[(size_t)(32 + quad * 8 + j) * HDIM + jg]);
    }
    if (quad == 0) {
        #pragma unroll
        for (int j = 0; j < 8; ++j)
            Bw2[j] = (short)f2bf(W1[(size_t)(HDIM + j) * HDIM + jg]);
    } else {
        Bw2 = zero8();
    }

    {
        const bf16x8 a0 = *reinterpret_cast<const bf16x8*>(&hbuf[0][col * S_H + quad * 8]);
        const bf16x8 a1 = *reinterpret_cast<const bf16x8*>(&hbuf[0][col * S_H + 32 + quad * 8]);
        bf16x8 axs;
        if (quad == 0) {
            int node = node0 + col;
            if (node >= NNODES) node = 0;
            axs = cvt8(x_stat + (size_t)node * STATF);
        } else {
            axs = zero8();
        }
        const f32x4 z4 = {0.f, 0.f, 0.f, 0.f};
        f32x4 aw;
        aw = __builtin_amdgcn_mfma_f32_16x16x32_bf16(a0, Bw0, z4, 0, 0, 0);
        aw = __builtin_amdgcn_mfma_f32_16x16x32_bf16(a1, Bw1, aw, 0, 0, 0);
        aw = __builtin_amdgcn_mfma_f32_16x16x32_bf16(axs, Bw2, aw, 0, 0, 0);
        #pragma unroll
        for (int r = 0; r < 4; ++r) {
            const int node = node0 + quad * 4 + r;
            if (node < NNODES) t1[(size_t)node * HDIM + jg] = f2bf(aw[r]);
        }
    }
}

// ---------------------------------------------------------------------------
// CSR build phase 1: in-degree histogram (int atomics).
// ---------------------------------------------------------------------------
__global__ __launch_bounds__(256) void hist_kernel(
    const int* __restrict__ dstv, int* __restrict__ deg)
{
    const int e = blockIdx.x * 256 + threadIdx.x;
    if (e < NEDGES) atomicAdd(&deg[dstv[e]], 1);
}

// ---------------------------------------------------------------------------
// CSR build phase 2: exclusive scan of deg -> offs, cursor copy.
// ---------------------------------------------------------------------------
__global__ __launch_bounds__(1024) void scan_kernel(
    const int* __restrict__ deg, int* __restrict__ offs, int* __restrict__ cursor)
{
    __shared__ int wsum[16];
    const int tid = (int)threadIdx.x;
    const int lane = tid & 63;
    const int wid = tid >> 6;
    int carry = 0;

    for (int base = 0; base < NNODES; base += 1024) {
        const int idx = base + tid;
        const int v = (idx < NNODES) ? deg[idx] : 0;
        int incl = v;
        #pragma unroll
        for (int off = 1; off < 64; off <<= 1) {
            int t = __shfl_up(incl, off, 64);
            if (lane >= off) incl += t;
        }
        if (lane == 63) wsum[wid] = incl;
        __syncthreads();
        if (wid == 0 && lane < 16) {
            int s = wsum[lane];
            #pragma unroll
            for (int off = 1; off < 16; off <<= 1) {
                int t = __shfl_up(s, off, 16);
                if ((lane & 15) >= off) s += t;
            }
            wsum[lane] = s;
        }
        __syncthreads();
        const int wbase = (wid == 0) ? 0 : wsum[wid - 1];
        const int excl = carry + wbase + incl - v;
        if (idx < NNODES) { offs[idx] = excl; cursor[idx] = excl; }
        carry += wsum[15];
        __syncthreads();
    }
    if (tid == 0) offs[NNODES] = carry;
}

// ---------------------------------------------------------------------------
// CSR build phase 3: slot fill, XCD dst-range partitioned (see R7 notes).
// ---------------------------------------------------------------------------
__global__ __launch_bounds__(256) void fill_kernel(
    const int* __restrict__ srcv, const int* __restrict__ dstv,
    const float* __restrict__ ew, int* __restrict__ cursor,
    unsigned* __restrict__ csr)
{
    const int range = (int)blockIdx.x & 7;
    const int chunk = (int)blockIdx.x >> 3;
    const int e = chunk * 256 + (int)threadIdx.x;
    if (e >= NEDGES) return;
    const int d = dstv[e];
    const int lo = range * (NNODES / 8);
    const int hi = (range == 7) ? NNODES : lo + (NNODES / 8);
    if (d < lo || d >= hi) return;
    const int pos = atomicAdd(&cursor[d], 1);
    csr[pos] = (unsigned)srcv[e] | ((unsigned)f2bf(ew[e]) << 16);
}

// ---------------------------------------------------------------------------
// Gather-reduce per dst node: one wave per node, lane = feature. 8-deep ILP.
// ---------------------------------------------------------------------------
__global__ __launch_bounds__(256) void gather_kernel(
    const unsigned short* __restrict__ tsrc, const int* __restrict__ offs,
    const unsigned* __restrict__ csr, float* __restrict__ agg)
{
    const int node = blockIdx.x * 4 + (threadIdx.x >> 6);
    const int lane = threadIdx.x & 63;
    if (node >= NNODES) return;
    const int beg = offs[node];
    const int end = offs[node + 1];
    float acc = 0.f;
    int i = beg;
    for (; i + 8 <= end; i += 8) {   // 8 independent gathers in flight
        unsigned p[8];
        float v[8];
        #pragma unroll
        for (int k = 0; k < 8; ++k) p[k] = csr[i + k];
        #pragma unroll
        for (int k = 0; k < 8; ++k)
            v[k] = bf2f(tsrc[(size_t)(p[k] & 0xFFFFu) * HDIM + lane]);
        #pragma unroll
        for (int k = 0; k < 8; ++k)
            acc += __uint_as_float(p[k] & 0xFFFF0000u) * v[k];
    }
    for (; i < end; ++i) {
        const unsigned p = csr[i];
        acc += __uint_as_float(p & 0xFFFF0000u)
             * bf2f(tsrc[(size_t)(p & 0xFFFFu) * HDIM + lane]);
    }
    agg[(size_t)node * HDIM + lane] = acc;
}

// ---------------------------------------------------------------------------
// MFMA transform: t2 = relu(agg + b1) @ W2, bf16 out.
// Block = 64 nodes x 4 waves; wave w computes features [16w,16w+16) for all
// 4 M-tiles. A built in registers from coalesced fp32 loads (no LDS).
// ---------------------------------------------------------------------------
__global__ __launch_bounds__(256) void transform_kernel(
    const float* __restrict__ agg, const float* __restrict__ bias,
    const float* __restrict__ W, unsigned short* __restrict__ out)
{
    const int lane = (int)threadIdx.x & 63;
    const int w = __builtin_amdgcn_readfirstlane((int)(threadIdx.x >> 6));
    const int col = lane & 15;
    const int quad = lane >> 4;
    const int node0 = (int)blockIdx.x * 64;
    const int jg = w * 16 + col;

    // B-frags: B[k=quad*8+j][n=jg] = W[(quad*8+j)*64 + jg], two K-tiles
    bf16x8 Bw0, Bw1;
    #pragma unroll
    for (int j = 0; j < 8; ++j) {
        Bw0[j] = (short)f2bf(W[(size_t)(quad * 8 + j) * HDIM + jg]);
        Bw1[j] = (short)f2bf(W[(size_t)(32 + quad * 8 + j) * HDIM + jg]);
    }
    // bias for this lane's k-slice
    float bk0[8], bk1[8];
    #pragma unroll
    for (int j = 0; j < 8; ++j) {
        bk0[j] = bias[quad * 8 + j];
        bk1[j] = bias[32 + quad * 8 + j];
    }

    #pragma unroll
    for (int mt = 0; mt < 4; ++mt) {
        int node = node0 + mt * 16 + col;
        const bool valid_a = node < NNODES;
        if (!valid_a) node = 0;
        const float* arow = agg + (size_t)node * HDIM;
        bf16x8 a0, a1;
        #pragma unroll
        for (int j = 0; j < 8; ++j) {
            a0[j] = (short)f2bf(fmaxf(arow[quad * 8 + j] + bk0[j], 0.f));
            a1[j] = (short)f2bf(fmaxf(arow[32 + quad * 8 + j] + bk1[j], 0.f));
        }
        const f32x4 z4 = {0.f, 0.f, 0.f, 0.f};
        f32x4 aw;
        aw = __builtin_amdgcn_mfma_f32_16x16x32_bf16(a0, Bw0, z4, 0, 0, 0);
        aw = __builtin_amdgcn_mfma_f32_16x16x32_bf16(a1, Bw1, aw, 0, 0, 0);
        #pragma unroll
        for (int r = 0; r < 4; ++r) {
            const int nn = node0 + mt * 16 + quad * 4 + r;
            if (nn < NNODES) out[(size_t)nn * HDIM + jg] = f2bf(aw[r]);
        }
    }
}

// ---------------------------------------------------------------------------
// Heads: h2 = relu(agg2 + b2); aqi = h2.Wa + ba; pm = h2.Wp + bp
// ---------------------------------------------------------------------------
__global__ __launch_bounds__(256) void head_kernel(
    const float* __restrict__ agg2, const float* __restrict__ b2,
    const float* __restrict__ Wa, const float* __restrict__ ba,
    const float* __restrict__ Wp, const float* __restrict__ bp,
    float* __restrict__ out)
{
    const int node = blockIdx.x * 256 + threadIdx.x;
    if (node >= NNODES) return;
    const float* arow = agg2 + (size_t)node * HDIM;
    float sa = 0.f, sp = 0.f;
    #pragma unroll
    for (int c = 0; c < 16; ++c) {
        float4 v = *reinterpret_cast<const float4*>(arow + c * 4);
        float h0 = fmaxf(v.x + b2[c*4+0], 0.f);
        float h1 = fmaxf(v.y + b2[c*4+1], 0.f);
        float h2 = fmaxf(v.z + b2[c*4+2], 0.f);
        float h3 = fmaxf(v.w + b2[c*4+3], 0.f);
        sa += h0 * Wa[c*4+0] + h1 * Wa[c*4+1] + h2 * Wa[c*4+2] + h3 * Wa[c*4+3];
        sp += h0 * Wp[c*4+0] + h1 * Wp[c*4+1] + h2 * Wp[c*4+2] + h3 * Wp[c*4+3];
    }
    out[node] = sa + ba[0];
    out[NNODES + node] = sp + bp[0];
}

extern "C" void kernel_launch(void* const* d_in, const int* in_sizes, int n_in,
                              void* d_out, int out_size, void* d_ws, size_t ws_size,
                              hipStream_t stream)
{
    const float* x_dyn  = (const float*)d_in[0];
    const float* x_stat = (const float*)d_in[1];
    const int*   eidx   = (const int*)  d_in[2];
    const float* ew     = (const float*)d_in[3];
    const float* Wih    = (const float*)d_in[4];
    const float* Whh    = (const float*)d_in[5];
    const float* bih    = (const float*)d_in[6];
    const float* bhh    = (const float*)d_in[7];
    const float* W1     = (const float*)d_in[8];
    const float* b1     = (const float*)d_in[9];
    const float* W2     = (const float*)d_in[10];
    const float* b2     = (const float*)d_in[11];
    const float* Wa     = (const float*)d_in[12];
    const float* ba     = (const float*)d_in[13];
    const float* Wp     = (const float*)d_in[14];
    const float* bp     = (const float*)d_in[15];

    const int* srcv = eidx;
    const int* dstv = eidx + NEDGES;

    // workspace layout (4B units)
    const size_t NH = (size_t)NNODES * HDIM;    // 3.2M elements
    float* ws   = (float*)d_ws;
    unsigned short* t1 = (unsigned short*)ws;                 // [NH] bf16
    unsigned short* t2 = (unsigned short*)(ws + NH / 2);      // [NH] bf16
    float* agg1 = ws + NH;            // [NH] fp32
    float* agg2 = ws + 2 * NH;        // [NH] fp32
    int*   deg    = (int*)(ws + 3 * NH);              // [NNODES]
    int*   offs   = deg + NNODES;                     // [NNODES+1]
    int*   cursor = offs + NNODES + 1;                // [NNODES]
    unsigned* csr = (unsigned*)(cursor + NNODES);     // [NEDGES] packed (src|w)

    dim3 blk(256);

    // ---- GRU + W1 (longest independent work first) ----
    gru_w1_kernel<<<dim3((NNODES + NB - 1) / NB), blk, 0, stream>>>(
        x_dyn, x_stat, Wih, Whh, bih, bhh, W1, t1);

    // ---- CSR build (once, reused by both layers) ----
    hipMemsetAsync(deg, 0, (size_t)NNODES * sizeof(int), stream);
    hist_kernel<<<dim3((NEDGES + 255) / 256), blk, 0, stream>>>(dstv, deg);
    scan_kernel<<<dim3(1), dim3(1024), 0, stream>>>(deg, offs, cursor);
    fill_kernel<<<dim3(((NEDGES + 255) / 256) * 8), blk, 0, stream>>>(
        srcv, dstv, ew, cursor, csr);

    // ---- layer 1 ----
    gather_kernel<<<dim3((NNODES + 3) / 4), blk, 0, stream>>>(t1, offs, csr, agg1);
    transform_kernel<<<dim3((NNODES + 63) / 64), blk, 0, stream>>>(agg1, b1, W2, t2);

    // ---- layer 2 ----
    gather_kernel<<<dim3((NNODES + 3) / 4), blk, 0, stream>>>(t2, offs, csr, agg2);
    head_kernel<<<dim3((NNODES + 255) / 256), blk, 0, stream>>>(
        agg2, b2, Wa, ba, Wp, bp, (float*)d_out);
}

// Round 10
// 510.616 us; speedup vs baseline: 1.2663x; 1.2663x over previous
//
#include <hip/hip_runtime.h>
#include <cstdint>
#include <cstddef>

#define NNODES 50000
#define TT 24
#define DYNF 16
#define STATF 8
#define HDIM 64
#define NEDGES 1600000
#define NB 32   // nodes per GRU block (16 regressed: VGPR cap -> weight spill)

typedef __attribute__((ext_vector_type(8))) short bf16x8;
typedef __attribute__((ext_vector_type(4))) float f32x4;

// fp32 -> bf16 with round-to-nearest-even
__device__ __forceinline__ unsigned short f2bf(float f) {
    unsigned u = __float_as_uint(f);
    u = (u + 0x7FFFu + ((u >> 16) & 1u)) >> 16;
    return (unsigned short)u;
}
__device__ __forceinline__ float bf2f(unsigned short s) {
    return __uint_as_float((unsigned)s << 16);
}
__device__ __forceinline__ bf16x8 cvt8(const float* __restrict__ p) {
    bf16x8 r;
    #pragma unroll
    for (int i = 0; i < 8; ++i) r[i] = (short)f2bf(p[i]);
    return r;
}
__device__ __forceinline__ bf16x8 zero8() {
    bf16x8 z;
    #pragma unroll
    for (int i = 0; i < 8; ++i) z[i] = 0;
    return z;
}
// robust fast tanh: no inf/inf NaN at extremes
__device__ __forceinline__ float fast_tanh(float x) {
    float e = __expf(2.f * x);
    return 1.f - 2.f * __builtin_amdgcn_rcpf(e + 1.f);
}

// ---------------------------------------------------------------------------
// MFMA GRU + fused W1 transform. Block = 32 nodes x 4 waves, bounds (256,4):
// VGPR ~60, weights stay register-resident (NB=16/(256,8) spilled — R9).
// Per step: G(32x192) = [h|x_t](32x96) @ B(96x192), 16x16x32 bf16 MFMA.
// Sigmoid pair shares one rcp: q=rcp(dr*dz); R=q*dz; Z=q*dr.
// ---------------------------------------------------------------------------
__global__ __launch_bounds__(256, 4) void gru_w1_kernel(
    const float* __restrict__ x_dyn, const float* __restrict__ x_stat,
    const float* __restrict__ Wih, const float* __restrict__ Whh,
    const float* __restrict__ bih, const float* __restrict__ bhh,
    const float* __restrict__ W1, unsigned short* __restrict__ t1)
{
    constexpr int S_H = 72;   // bf16 units per hbuf row (144B: 16B-aligned)
    constexpr int S_X = 40;   // bf16 units per xbuf row
    __shared__ short hbuf[2][NB * S_H];   // [node][feature] bf16, dbuf
    __shared__ short xbuf[2][NB * S_X];   // [node][k] bf16; k 16..31 zeroed

    const int tid = (int)threadIdx.x;
    const int lane = tid & 63;
    const int w = __builtin_amdgcn_readfirstlane(tid >> 6);  // wave 0..3
    const int col = lane & 15;
    const int quad = lane >> 4;
    const int node0 = (int)blockIdx.x * NB;

    bf16x8 Bh[3][2];
    bf16x8 Bx[3];
    #pragma unroll
    for (int g = 0; g < 3; ++g) {
        const int n = (w + g * 4) * 16 + col;   // gate row in [0,192)
        #pragma unroll
        for (int kt = 0; kt < 2; ++kt)
            Bh[g][kt] = cvt8(Whh + (size_t)n * HDIM + kt * 32 + quad * 8);
        Bx[g] = (quad < 2) ? cvt8(Wih + (size_t)n * DYNF + quad * 8) : zero8();
    }

    const int jg = w * 16 + col;                 // feature 0..63
    const float b_r  = bih[jg]        + bhh[jg];
    const float b_z  = bih[HDIM + jg] + bhh[HDIM + jg];
    const float b_xn = bih[2 * HDIM + jg];
    const float b_hn = bhh[2 * HDIM + jg];

    for (int i = tid; i < NB * S_H; i += 256) hbuf[0][i] = 0;

    // stage x_t: 32 nodes x 8 float2 chunks = 256 tasks
    auto stage_x = [&](int t, int b) {
        const int nd = tid >> 3, c = tid & 7;
        int node = node0 + nd;
        if (node >= NNODES) node = 0;
        const float2 v = *reinterpret_cast<const float2*>(
            x_dyn + (size_t)node * (TT * DYNF) + t * DYNF + c * 2);
        unsigned pk = (unsigned)f2bf(v.x) | ((unsigned)f2bf(v.y) << 16);
        *reinterpret_cast<unsigned*>(&xbuf[b][nd * S_X + c * 2]) = pk;
        *reinterpret_cast<unsigned*>(&xbuf[b][nd * S_X + 16 + c * 2]) = 0u;
    };
    stage_x(0, 0);

    float hprev[2][4];
    #pragma unroll
    for (int mt = 0; mt < 2; ++mt)
        #pragma unroll
        for (int r = 0; r < 4; ++r) hprev[mt][r] = 0.f;

    for (int t = 0; t < TT; ++t) {
        const int rb = t & 1;
        __syncthreads();   // hbuf[rb], xbuf[rb] ready

        f32x4 accr[2], accz[2], accnh[2], accnx[2];
        #pragma unroll
        for (int mt = 0; mt < 2; ++mt) {
            const int nd = mt * 16 + col;   // A-frag: m = lane&15 within tile
            const bf16x8 a0 = *reinterpret_cast<const bf16x8*>(&hbuf[rb][nd * S_H + quad * 8]);
            const bf16x8 a1 = *reinterpret_cast<const bf16x8*>(&hbuf[rb][nd * S_H + 32 + quad * 8]);
            const bf16x8 ax = *reinterpret_cast<const bf16x8*>(&xbuf[rb][nd * S_X + quad * 8]);
            const f32x4 z4 = {0.f, 0.f, 0.f, 0.f};
            accr[mt]  = __builtin_amdgcn_mfma_f32_16x16x32_bf16(a0, Bh[0][0], z4, 0, 0, 0);
            accr[mt]  = __builtin_amdgcn_mfma_f32_16x16x32_bf16(a1, Bh[0][1], accr[mt], 0, 0, 0);
            accr[mt]  = __builtin_amdgcn_mfma_f32_16x16x32_bf16(ax, Bx[0],    accr[mt], 0, 0, 0);
            accz[mt]  = __builtin_amdgcn_mfma_f32_16x16x32_bf16(a0, Bh[1][0], z4, 0, 0, 0);
            accz[mt]  = __builtin_amdgcn_mfma_f32_16x16x32_bf16(a1, Bh[1][1], accz[mt], 0, 0, 0);
            accz[mt]  = __builtin_amdgcn_mfma_f32_16x16x32_bf16(ax, Bx[1],    accz[mt], 0, 0, 0);
            accnh[mt] = __builtin_amdgcn_mfma_f32_16x16x32_bf16(a0, Bh[2][0], z4, 0, 0, 0);
            accnh[mt] = __builtin_amdgcn_mfma_f32_16x16x32_bf16(a1, Bh[2][1], accnh[mt], 0, 0, 0);
            accnx[mt] = __builtin_amdgcn_mfma_f32_16x16x32_bf16(ax, Bx[2],    z4, 0, 0, 0);
        }

        if (t + 1 < TT) stage_x(t + 1, rb ^ 1);  // overlap with MFMA drain

        #pragma unroll
        for (int mt = 0; mt < 2; ++mt) {
            #pragma unroll
            for (int r = 0; r < 4; ++r) {
                const float dr = 1.f + __expf(-(accr[mt][r] + b_r));
                const float dz = 1.f + __expf(-(accz[mt][r] + b_z));
                const float q  = __builtin_amdgcn_rcpf(dr * dz);
                const float R  = q * dz;           // = 1/dr
                const float Z  = q * dr;           // = 1/dz
                const float Nn = fast_tanh(accnx[mt][r] + b_xn + R * (accnh[mt][r] + b_hn));
                const float hn = Nn + Z * (hprev[mt][r] - Nn);
                hprev[mt][r] = hn;
                hbuf[rb ^ 1][(mt * 16 + quad * 4 + r) * S_H + jg] = (short)f2bf(hn);
            }
        }
    }
    __syncthreads();   // final h in hbuf[0]

    // ---- fused W1: t1 = [h | x_stat] @ W1 (bf16 out) ----
    bf16x8 Bw0, Bw1, Bw2;
    #pragma unroll
    for (int j = 0; j < 8; ++j) {
        Bw0[j] = (short)f2bf(W1[(size_t)(quad * 8 + j) * HDIM + jg]);
        Bw1[j] = (short)f2bf(W1[(size_t)(32 + quad * 8 + j) * HDIM + jg]);
    }
    if (quad == 0) {
        #pragma unroll
        for (int j = 0; j < 8; ++j)
            Bw2[j] = (short)f2bf(W1[(size_t)(HDIM + j) * HDIM + jg]);
    } else {
        Bw2 = zero8();
    }

    #pragma unroll
    for (int mt = 0; mt < 2; ++mt) {
        const int nd = mt * 16 + col;
        const bf16x8 a0 = *reinterpret_cast<const bf16x8*>(&hbuf[0][nd * S_H + quad * 8]);
        const bf16x8 a1 = *reinterpret_cast<const bf16x8*>(&hbuf[0][nd * S_H + 32 + quad * 8]);
        bf16x8 axs;
        if (quad == 0) {
            int node = node0 + nd;
            if (node >= NNODES) node = 0;
            axs = cvt8(x_stat + (size_t)node * STATF);
        } else {
            axs = zero8();
        }
        const f32x4 z4 = {0.f, 0.f, 0.f, 0.f};
        f32x4 aw;
        aw = __builtin_amdgcn_mfma_f32_16x16x32_bf16(a0, Bw0, z4, 0, 0, 0);
        aw = __builtin_amdgcn_mfma_f32_16x16x32_bf16(a1, Bw1, aw, 0, 0, 0);
        aw = __builtin_amdgcn_mfma_f32_16x16x32_bf16(axs, Bw2, aw, 0, 0, 0);
        #pragma unroll
        for (int r = 0; r < 4; ++r) {
            const int node = node0 + mt * 16 + quad * 4 + r;
            if (node < NNODES) t1[(size_t)node * HDIM + jg] = f2bf(aw[r]);
        }
    }
}

// ---------------------------------------------------------------------------
// CSR build phase 1: in-degree histogram (int atomics).
// ---------------------------------------------------------------------------
__global__ __launch_bounds__(256) void hist_kernel(
    const int* __restrict__ dstv, int* __restrict__ deg)
{
    const int e = blockIdx.x * 256 + threadIdx.x;
    if (e < NEDGES) atomicAdd(&deg[dstv[e]], 1);
}

// ---------------------------------------------------------------------------
// CSR build phase 2: exclusive scan of deg -> offs, cursor copy.
// ---------------------------------------------------------------------------
__global__ __launch_bounds__(1024) void scan_kernel(
    const int* __restrict__ deg, int* __restrict__ offs, int* __restrict__ cursor)
{
    __shared__ int wsum[16];
    const int tid = (int)threadIdx.x;
    const int lane = tid & 63;
    const int wid = tid >> 6;
    int carry = 0;

    for (int base = 0; base < NNODES; base += 1024) {
        const int idx = base + tid;
        const int v = (idx < NNODES) ? deg[idx] : 0;
        int incl = v;
        #pragma unroll
        for (int off = 1; off < 64; off <<= 1) {
            int t = __shfl_up(incl, off, 64);
            if (lane >= off) incl += t;
        }
        if (lane == 63) wsum[wid] = incl;
        __syncthreads();
        if (wid == 0 && lane < 16) {
            int s = wsum[lane];
            #pragma unroll
            for (int off = 1; off < 16; off <<= 1) {
                int t = __shfl_up(s, off, 16);
                if ((lane & 15) >= off) s += t;
            }
            wsum[lane] = s;
        }
        __syncthreads();
        const int wbase = (wid == 0) ? 0 : wsum[wid - 1];
        const int excl = carry + wbase + incl - v;
        if (idx < NNODES) { offs[idx] = excl; cursor[idx] = excl; }
        carry += wsum[15];
        __syncthreads();
    }
    if (tid == 0) offs[NNODES] = carry;
}

// ---------------------------------------------------------------------------
// CSR build phase 3: slot fill, XCD dst-range partitioned (see R7 notes).
// ---------------------------------------------------------------------------
__global__ __launch_bounds__(256) void fill_kernel(
    const int* __restrict__ srcv, const int* __restrict__ dstv,
    const float* __restrict__ ew, int* __restrict__ cursor,
    unsigned* __restrict__ csr)
{
    const int range = (int)blockIdx.x & 7;
    const int chunk = (int)blockIdx.x >> 3;
    const int e = chunk * 256 + (int)threadIdx.x;
    if (e >= NEDGES) return;
    const int d = dstv[e];
    const int lo = range * (NNODES / 8);
    const int hi = (range == 7) ? NNODES : lo + (NNODES / 8);
    if (d < lo || d >= hi) return;
    const int pos = atomicAdd(&cursor[d], 1);
    csr[pos] = (unsigned)srcv[e] | ((unsigned)f2bf(ew[e]) << 16);
}

// ---------------------------------------------------------------------------
// Gather-reduce per dst node: one wave per node, lane = feature. 8-deep ILP.
// ---------------------------------------------------------------------------
__global__ __launch_bounds__(256) void gather_kernel(
    const unsigned short* __restrict__ tsrc, const int* __restrict__ offs,
    const unsigned* __restrict__ csr, float* __restrict__ agg)
{
    const int node = blockIdx.x * 4 + (threadIdx.x >> 6);
    const int lane = threadIdx.x & 63;
    if (node >= NNODES) return;
    const int beg = offs[node];
    const int end = offs[node + 1];
    float acc = 0.f;
    int i = beg;
    for (; i + 8 <= end; i += 8) {   // 8 independent gathers in flight
        unsigned p[8];
        float v[8];
        #pragma unroll
        for (int k = 0; k < 8; ++k) p[k] = csr[i + k];
        #pragma unroll
        for (int k = 0; k < 8; ++k)
            v[k] = bf2f(tsrc[(size_t)(p[k] & 0xFFFFu) * HDIM + lane]);
        #pragma unroll
        for (int k = 0; k < 8; ++k)
            acc += __uint_as_float(p[k] & 0xFFFF0000u) * v[k];
    }
    for (; i < end; ++i) {
        const unsigned p = csr[i];
        acc += __uint_as_float(p & 0xFFFF0000u)
             * bf2f(tsrc[(size_t)(p & 0xFFFFu) * HDIM + lane]);
    }
    agg[(size_t)node * HDIM + lane] = acc;
}

// ---------------------------------------------------------------------------
// MFMA transform: t2 = relu(agg + b1) @ W2, bf16 out.
// Block = 64 nodes x 4 waves; A built in registers from coalesced loads.
// ---------------------------------------------------------------------------
__global__ __launch_bounds__(256) void transform_kernel(
    const float* __restrict__ agg, const float* __restrict__ bias,
    const float* __restrict__ W, unsigned short* __restrict__ out)
{
    const int lane = (int)threadIdx.x & 63;
    const int w = __builtin_amdgcn_readfirstlane((int)(threadIdx.x >> 6));
    const int col = lane & 15;
    const int quad = lane >> 4;
    const int node0 = (int)blockIdx.x * 64;
    const int jg = w * 16 + col;

    bf16x8 Bw0, Bw1;
    #pragma unroll
    for (int j = 0; j < 8; ++j) {
        Bw0[j] = (short)f2bf(W[(size_t)(quad * 8 + j) * HDIM + jg]);
        Bw1[j] = (short)f2bf(W[(size_t)(32 + quad * 8 + j) * HDIM + jg]);
    }
    float bk0[8], bk1[8];
    #pragma unroll
    for (int j = 0; j < 8; ++j) {
        bk0[j] = bias[quad * 8 + j];
        bk1[j] = bias[32 + quad * 8 + j];
    }

    #pragma unroll
    for (int mt = 0; mt < 4; ++mt) {
        int node = node0 + mt * 16 + col;
        if (node >= NNODES) node = 0;
        const float* arow = agg + (size_t)node * HDIM;
        bf16x8 a0, a1;
        #pragma unroll
        for (int j = 0; j < 8; ++j) {
            a0[j] = (short)f2bf(fmaxf(arow[quad * 8 + j] + bk0[j], 0.f));
            a1[j] = (short)f2bf(fmaxf(arow[32 + quad * 8 + j] + bk1[j], 0.f));
        }
        const f32x4 z4 = {0.f, 0.f, 0.f, 0.f};
        f32x4 aw;
        aw = __builtin_amdgcn_mfma_f32_16x16x32_bf16(a0, Bw0, z4, 0, 0, 0);
        aw = __builtin_amdgcn_mfma_f32_16x16x32_bf16(a1, Bw1, aw, 0, 0, 0);
        #pragma unroll
        for (int r = 0; r < 4; ++r) {
            const int nn = node0 + mt * 16 + quad * 4 + r;
            if (nn < NNODES) out[(size_t)nn * HDIM + jg] = f2bf(aw[r]);
        }
    }
}

// ---------------------------------------------------------------------------
// Heads: h2 = relu(agg2 + b2); aqi = h2.Wa + ba; pm = h2.Wp + bp
// ---------------------------------------------------------------------------
__global__ __launch_bounds__(256) void head_kernel(
    const float* __restrict__ agg2, const float* __restrict__ b2,
    const float* __restrict__ Wa, const float* __restrict__ ba,
    const float* __restrict__ Wp, const float* __restrict__ bp,
    float* __restrict__ out)
{
    const int node = blockIdx.x * 256 + threadIdx.x;
    if (node >= NNODES) return;
    const float* arow = agg2 + (size_t)node * HDIM;
    float sa = 0.f, sp = 0.f;
    #pragma unroll
    for (int c = 0; c < 16; ++c) {
        float4 v = *reinterpret_cast<const float4*>(arow + c * 4);
        float h0 = fmaxf(v.x + b2[c*4+0], 0.f);
        float h1 = fmaxf(v.y + b2[c*4+1], 0.f);
        float h2 = fmaxf(v.z + b2[c*4+2], 0.f);
        float h3 = fmaxf(v.w + b2[c*4+3], 0.f);
        sa += h0 * Wa[c*4+0] + h1 * Wa[c*4+1] + h2 * Wa[c*4+2] + h3 * Wa[c*4+3];
        sp += h0 * Wp[c*4+0] + h1 * Wp[c*4+1] + h2 * Wp[c*4+2] + h3 * Wp[c*4+3];
    }
    out[node] = sa + ba[0];
    out[NNODES + node] = sp + bp[0];
}

extern "C" void kernel_launch(void* const* d_in, const int* in_sizes, int n_in,
                              void* d_out, int out_size, void* d_ws, size_t ws_size,
                              hipStream_t stream)
{
    const float* x_dyn  = (const float*)d_in[0];
    const float* x_stat = (const float*)d_in[1];
    const int*   eidx   = (const int*)  d_in[2];
    const float* ew     = (const float*)d_in[3];
    const float* Wih    = (const float*)d_in[4];
    const float* Whh    = (const float*)d_in[5];
    const float* bih    = (const float*)d_in[6];
    const float* bhh    = (const float*)d_in[7];
    const float* W1     = (const float*)d_in[8];
    const float* b1     = (const float*)d_in[9];
    const float* W2     = (const float*)d_in[10];
    const float* b2     = (const float*)d_in[11];
    const float* Wa     = (const float*)d_in[12];
    const float* ba     = (const float*)d_in[13];
    const float* Wp     = (const float*)d_in[14];
    const float* bp     = (const float*)d_in[15];

    const int* srcv = eidx;
    const int* dstv = eidx + NEDGES;

    // workspace layout (4B units)
    const size_t NH = (size_t)NNODES * HDIM;    // 3.2M elements
    float* ws   = (float*)d_ws;
    unsigned short* t1 = (unsigned short*)ws;                 // [NH] bf16
    unsigned short* t2 = (unsigned short*)(ws + NH / 2);      // [NH] bf16
    float* agg1 = ws + NH;            // [NH] fp32
    float* agg2 = ws + 2 * NH;        // [NH] fp32
    int*   deg    = (int*)(ws + 3 * NH);              // [NNODES]
    int*   offs   = deg + NNODES;                     // [NNODES+1]
    int*   cursor = offs + NNODES + 1;                // [NNODES]
    unsigned* csr = (unsigned*)(cursor + NNODES);     // [NEDGES] packed (src|w)

    dim3 blk(256);

    // ---- GRU + W1 (longest independent work first) ----
    gru_w1_kernel<<<dim3((NNODES + NB - 1) / NB), blk, 0, stream>>>(
        x_dyn, x_stat, Wih, Whh, bih, bhh, W1, t1);

    // ---- CSR build (once, reused by both layers) ----
    hipMemsetAsync(deg, 0, (size_t)NNODES * sizeof(int), stream);
    hist_kernel<<<dim3((NEDGES + 255) / 256), blk, 0, stream>>>(dstv, deg);
    scan_kernel<<<dim3(1), dim3(1024), 0, stream>>>(deg, offs, cursor);
    fill_kernel<<<dim3(((NEDGES + 255) / 256) * 8), blk, 0, stream>>>(
        srcv, dstv, ew, cursor, csr);

    // ---- layer 1 ----
    gather_kernel<<<dim3((NNODES + 3) / 4), blk, 0, stream>>>(t1, offs, csr, agg1);
    transform_kernel<<<dim3((NNODES + 63) / 64), blk, 0, stream>>>(agg1, b1, W2, t2);

    // ---- layer 2 ----
    gather_kernel<<<dim3((NNODES + 3) / 4), blk, 0, stream>>>(t2, offs, csr, agg2);
    head_kernel<<<dim3((NNODES + 255) / 256), blk, 0, stream>>>(
        agg2, b2, Wa, ba, Wp, bp, (float*)d_out);
}

// Round 11
// 493.868 us; speedup vs baseline: 1.3093x; 1.0339x over previous
//
#include <hip/hip_runtime.h>
#include <cstdint>
#include <cstddef>

#define NNODES 50000
#define TT 24
#define DYNF 16
#define STATF 8
#define HDIM 64
#define NEDGES 1600000
#define NB 32   // nodes per GRU block (16 regressed: VGPR cap -> weight spill)

typedef __attribute__((ext_vector_type(8))) short bf16x8;
typedef __attribute__((ext_vector_type(4))) float f32x4;

// fp32 -> bf16 with round-to-nearest-even
__device__ __forceinline__ unsigned short f2bf(float f) {
    unsigned u = __float_as_uint(f);
    u = (u + 0x7FFFu + ((u >> 16) & 1u)) >> 16;
    return (unsigned short)u;
}
__device__ __forceinline__ float bf2f(unsigned short s) {
    return __uint_as_float((unsigned)s << 16);
}
__device__ __forceinline__ bf16x8 cvt8(const float* __restrict__ p) {
    bf16x8 r;
    #pragma unroll
    for (int i = 0; i < 8; ++i) r[i] = (short)f2bf(p[i]);
    return r;
}
__device__ __forceinline__ bf16x8 zero8() {
    bf16x8 z;
    #pragma unroll
    for (int i = 0; i < 8; ++i) z[i] = 0;
    return z;
}
// robust fast tanh: no inf/inf NaN at extremes
__device__ __forceinline__ float fast_tanh(float x) {
    float e = __expf(2.f * x);
    return 1.f - 2.f * __builtin_amdgcn_rcpf(e + 1.f);
}

// ---------------------------------------------------------------------------
// MFMA GRU + fused W1 transform. Block = 32 nodes x 4 waves, bounds (256,4):
// VGPR ~60, weights stay register-resident (NB=16/(256,8) spilled — R9).
// (unchanged from R10)
// ---------------------------------------------------------------------------
__global__ __launch_bounds__(256, 4) void gru_w1_kernel(
    const float* __restrict__ x_dyn, const float* __restrict__ x_stat,
    const float* __restrict__ Wih, const float* __restrict__ Whh,
    const float* __restrict__ bih, const float* __restrict__ bhh,
    const float* __restrict__ W1, unsigned short* __restrict__ t1)
{
    constexpr int S_H = 72;   // bf16 units per hbuf row (144B: 16B-aligned)
    constexpr int S_X = 40;   // bf16 units per xbuf row
    __shared__ short hbuf[2][NB * S_H];   // [node][feature] bf16, dbuf
    __shared__ short xbuf[2][NB * S_X];   // [node][k] bf16; k 16..31 zeroed

    const int tid = (int)threadIdx.x;
    const int lane = tid & 63;
    const int w = __builtin_amdgcn_readfirstlane(tid >> 6);  // wave 0..3
    const int col = lane & 15;
    const int quad = lane >> 4;
    const int node0 = (int)blockIdx.x * NB;

    bf16x8 Bh[3][2];
    bf16x8 Bx[3];
    #pragma unroll
    for (int g = 0; g < 3; ++g) {
        const int n = (w + g * 4) * 16 + col;   // gate row in [0,192)
        #pragma unroll
        for (int kt = 0; kt < 2; ++kt)
            Bh[g][kt] = cvt8(Whh + (size_t)n * HDIM + kt * 32 + quad * 8);
        Bx[g] = (quad < 2) ? cvt8(Wih + (size_t)n * DYNF + quad * 8) : zero8();
    }

    const int jg = w * 16 + col;                 // feature 0..63
    const float b_r  = bih[jg]        + bhh[jg];
    const float b_z  = bih[HDIM + jg] + bhh[HDIM + jg];
    const float b_xn = bih[2 * HDIM + jg];
    const float b_hn = bhh[2 * HDIM + jg];

    for (int i = tid; i < NB * S_H; i += 256) hbuf[0][i] = 0;

    // stage x_t: 32 nodes x 8 float2 chunks = 256 tasks
    auto stage_x = [&](int t, int b) {
        const int nd = tid >> 3, c = tid & 7;
        int node = node0 + nd;
        if (node >= NNODES) node = 0;
        const float2 v = *reinterpret_cast<const float2*>(
            x_dyn + (size_t)node * (TT * DYNF) + t * DYNF + c * 2);
        unsigned pk = (unsigned)f2bf(v.x) | ((unsigned)f2bf(v.y) << 16);
        *reinterpret_cast<unsigned*>(&xbuf[b][nd * S_X + c * 2]) = pk;
        *reinterpret_cast<unsigned*>(&xbuf[b][nd * S_X + 16 + c * 2]) = 0u;
    };
    stage_x(0, 0);

    float hprev[2][4];
    #pragma unroll
    for (int mt = 0; mt < 2; ++mt)
        #pragma unroll
        for (int r = 0; r < 4; ++r) hprev[mt][r] = 0.f;

    for (int t = 0; t < TT; ++t) {
        const int rb = t & 1;
        __syncthreads();   // hbuf[rb], xbuf[rb] ready

        f32x4 accr[2], accz[2], accnh[2], accnx[2];
        #pragma unroll
        for (int mt = 0; mt < 2; ++mt) {
            const int nd = mt * 16 + col;   // A-frag: m = lane&15 within tile
            const bf16x8 a0 = *reinterpret_cast<const bf16x8*>(&hbuf[rb][nd * S_H + quad * 8]);
            const bf16x8 a1 = *reinterpret_cast<const bf16x8*>(&hbuf[rb][nd * S_H + 32 + quad * 8]);
            const bf16x8 ax = *reinterpret_cast<const bf16x8*>(&xbuf[rb][nd * S_X + quad * 8]);
            const f32x4 z4 = {0.f, 0.f, 0.f, 0.f};
            accr[mt]  = __builtin_amdgcn_mfma_f32_16x16x32_bf16(a0, Bh[0][0], z4, 0, 0, 0);
            accr[mt]  = __builtin_amdgcn_mfma_f32_16x16x32_bf16(a1, Bh[0][1], accr[mt], 0, 0, 0);
            accr[mt]  = __builtin_amdgcn_mfma_f32_16x16x32_bf16(ax, Bx[0],    accr[mt], 0, 0, 0);
            accz[mt]  = __builtin_amdgcn_mfma_f32_16x16x32_bf16(a0, Bh[1][0], z4, 0, 0, 0);
            accz[mt]  = __builtin_amdgcn_mfma_f32_16x16x32_bf16(a1, Bh[1][1], accz[mt], 0, 0, 0);
            accz[mt]  = __builtin_amdgcn_mfma_f32_16x16x32_bf16(ax, Bx[1],    accz[mt], 0, 0, 0);
            accnh[mt] = __builtin_amdgcn_mfma_f32_16x16x32_bf16(a0, Bh[2][0], z4, 0, 0, 0);
            accnh[mt] = __builtin_amdgcn_mfma_f32_16x16x32_bf16(a1, Bh[2][1], accnh[mt], 0, 0, 0);
            accnx[mt] = __builtin_amdgcn_mfma_f32_16x16x32_bf16(ax, Bx[2],    z4, 0, 0, 0);
        }

        if (t + 1 < TT) stage_x(t + 1, rb ^ 1);  // overlap with MFMA drain

        #pragma unroll
        for (int mt = 0; mt < 2; ++mt) {
            #pragma unroll
            for (int r = 0; r < 4; ++r) {
                const float dr = 1.f + __expf(-(accr[mt][r] + b_r));
                const float dz = 1.f + __expf(-(accz[mt][r] + b_z));
                const float q  = __builtin_amdgcn_rcpf(dr * dz);
                const float R  = q * dz;           // = 1/dr
                const float Z  = q * dr;           // = 1/dz
                const float Nn = fast_tanh(accnx[mt][r] + b_xn + R * (accnh[mt][r] + b_hn));
                const float hn = Nn + Z * (hprev[mt][r] - Nn);
                hprev[mt][r] = hn;
                hbuf[rb ^ 1][(mt * 16 + quad * 4 + r) * S_H + jg] = (short)f2bf(hn);
            }
        }
    }
    __syncthreads();   // final h in hbuf[0]

    // ---- fused W1: t1 = [h | x_stat] @ W1 (bf16 out) ----
    bf16x8 Bw0, Bw1, Bw2;
    #pragma unroll
    for (int j = 0; j < 8; ++j) {
        Bw0[j] = (short)f2bf(W1[(size_t)(quad * 8 + j) * HDIM + jg]);
        Bw1[j] = (short)f2bf(W1[(size_t)(32 + quad * 8 + j) * HDIM + jg]);
    }
    if (quad == 0) {
        #pragma unroll
        for (int j = 0; j < 8; ++j)
            Bw2[j] = (short)f2bf(W1[(size_t)(HDIM + j) * HDIM + jg]);
    } else {
        Bw2 = zero8();
    }

    #pragma unroll
    for (int mt = 0; mt < 2; ++mt) {
        const int nd = mt * 16 + col;
        const bf16x8 a0 = *reinterpret_cast<const bf16x8*>(&hbuf[0][nd * S_H + quad * 8]);
        const bf16x8 a1 = *reinterpret_cast<const bf16x8*>(&hbuf[0][nd * S_H + 32 + quad * 8]);
        bf16x8 axs;
        if (quad == 0) {
            int node = node0 + nd;
            if (node >= NNODES) node = 0;
            axs = cvt8(x_stat + (size_t)node * STATF);
        } else {
            axs = zero8();
        }
        const f32x4 z4 = {0.f, 0.f, 0.f, 0.f};
        f32x4 aw;
        aw = __builtin_amdgcn_mfma_f32_16x16x32_bf16(a0, Bw0, z4, 0, 0, 0);
        aw = __builtin_amdgcn_mfma_f32_16x16x32_bf16(a1, Bw1, aw, 0, 0, 0);
        aw = __builtin_amdgcn_mfma_f32_16x16x32_bf16(axs, Bw2, aw, 0, 0, 0);
        #pragma unroll
        for (int r = 0; r < 4; ++r) {
            const int node = node0 + mt * 16 + quad * 4 + r;
            if (node < NNODES) t1[(size_t)node * HDIM + jg] = f2bf(aw[r]);
        }
    }
}

// ---------------------------------------------------------------------------
// CSR build phase 1: in-degree histogram (int atomics).
// ---------------------------------------------------------------------------
__global__ __launch_bounds__(256) void hist_kernel(
    const int* __restrict__ dstv, int* __restrict__ deg)
{
    const int e = blockIdx.x * 256 + threadIdx.x;
    if (e < NEDGES) atomicAdd(&deg[dstv[e]], 1);
}

// ---------------------------------------------------------------------------
// CSR build phase 2: exclusive scan of deg -> offs, cursor copy.
// ---------------------------------------------------------------------------
__global__ __launch_bounds__(1024) void scan_kernel(
    const int* __restrict__ deg, int* __restrict__ offs, int* __restrict__ cursor)
{
    __shared__ int wsum[16];
    const int tid = (int)threadIdx.x;
    const int lane = tid & 63;
    const int wid = tid >> 6;
    int carry = 0;

    for (int base = 0; base < NNODES; base += 1024) {
        const int idx = base + tid;
        const int v = (idx < NNODES) ? deg[idx] : 0;
        int incl = v;
        #pragma unroll
        for (int off = 1; off < 64; off <<= 1) {
            int t = __shfl_up(incl, off, 64);
            if (lane >= off) incl += t;
        }
        if (lane == 63) wsum[wid] = incl;
        __syncthreads();
        if (wid == 0 && lane < 16) {
            int s = wsum[lane];
            #pragma unroll
            for (int off = 1; off < 16; off <<= 1) {
                int t = __shfl_up(s, off, 16);
                if ((lane & 15) >= off) s += t;
            }
            wsum[lane] = s;
        }
        __syncthreads();
        const int wbase = (wid == 0) ? 0 : wsum[wid - 1];
        const int excl = carry + wbase + incl - v;
        if (idx < NNODES) { offs[idx] = excl; cursor[idx] = excl; }
        carry += wsum[15];
        __syncthreads();
    }
    if (tid == 0) offs[NNODES] = carry;
}

// ---------------------------------------------------------------------------
// CSR build phase 3: slot fill, XCD dst-range partitioned (see R7 notes).
// ---------------------------------------------------------------------------
__global__ __launch_bounds__(256) void fill_kernel(
    const int* __restrict__ srcv, const int* __restrict__ dstv,
    const float* __restrict__ ew, int* __restrict__ cursor,
    unsigned* __restrict__ csr)
{
    const int range = (int)blockIdx.x & 7;
    const int chunk = (int)blockIdx.x >> 3;
    const int e = chunk * 256 + (int)threadIdx.x;
    if (e >= NEDGES) return;
    const int d = dstv[e];
    const int lo = range * (NNODES / 8);
    const int hi = (range == 7) ? NNODES : lo + (NNODES / 8);
    if (d < lo || d >= hi) return;
    const int pos = atomicAdd(&cursor[d], 1);
    csr[pos] = (unsigned)srcv[e] | ((unsigned)f2bf(ew[e]) << 16);
}

// ---------------------------------------------------------------------------
// Gather-reduce, 2 edges per wave: lanes 0-31 edge i, lanes 32-63 edge i+1;
// each lane loads one uint = 2 bf16 features -> one 128B request per
// half-wave, VMEM instructions per edge HALVED vs 1-edge/wave. 4-deep ILP.
// Halves combined with shfl_xor(32); lanes 0-31 store float2 (256B/node).
// ---------------------------------------------------------------------------
__global__ __launch_bounds__(256) void gather_kernel(
    const unsigned short* __restrict__ tsrc, const int* __restrict__ offs,
    const unsigned* __restrict__ csr, float* __restrict__ agg)
{
    const int node = blockIdx.x * 4 + (threadIdx.x >> 6);
    const int lane = (int)threadIdx.x & 63;
    const int half = lane >> 5;
    const int fl = lane & 31;          // feature pair (2*fl, 2*fl+1)
    if (node >= NNODES) return;
    const int beg = offs[node];
    const int end = offs[node + 1];
    float ax = 0.f, ay = 0.f;
    int i = beg;
    for (; i + 8 <= end; i += 8) {     // 4 row-requests in flight per half
        unsigned p[4], pk[4];
        #pragma unroll
        for (int k = 0; k < 4; ++k) p[k] = csr[i + 2 * k + half];
        #pragma unroll
        for (int k = 0; k < 4; ++k)
            pk[k] = *reinterpret_cast<const unsigned*>(
                tsrc + (size_t)(p[k] & 0xFFFFu) * HDIM + 2 * fl);
        #pragma unroll
        for (int k = 0; k < 4; ++k) {
            const float wgt = __uint_as_float(p[k] & 0xFFFF0000u);
            ax += wgt * bf2f((unsigned short)(pk[k] & 0xFFFFu));
            ay += wgt * bf2f((unsigned short)(pk[k] >> 16));
        }
    }
    for (; i + 2 <= end; i += 2) {
        const unsigned p = csr[i + half];
        const unsigned pk = *reinterpret_cast<const unsigned*>(
            tsrc + (size_t)(p & 0xFFFFu) * HDIM + 2 * fl);
        const float wgt = __uint_as_float(p & 0xFFFF0000u);
        ax += wgt * bf2f((unsigned short)(pk & 0xFFFFu));
        ay += wgt * bf2f((unsigned short)(pk >> 16));
    }
    if (i < end) {                     // single leftover: half 0 contributes
        const unsigned p = csr[i];
        const unsigned pk = *reinterpret_cast<const unsigned*>(
            tsrc + (size_t)(p & 0xFFFFu) * HDIM + 2 * fl);
        const float wgt = (half == 0) ? __uint_as_float(p & 0xFFFF0000u) : 0.f;
        ax += wgt * bf2f((unsigned short)(pk & 0xFFFFu));
        ay += wgt * bf2f((unsigned short)(pk >> 16));
    }
    ax += __shfl_xor(ax, 32, 64);      // combine halves (both sides get sum)
    ay += __shfl_xor(ay, 32, 64);
    if (half == 0) {
        float2 o; o.x = ax; o.y = ay;
        *reinterpret_cast<float2*>(agg + (size_t)node * HDIM + 2 * fl) = o;
    }
}

// ---------------------------------------------------------------------------
// Gather + fused head for layer 2: same 2-edge gather; then
// h = relu(acc + b2); sa = h.Wa; sp = h.Wp reduced across lanes.
// Kills head_kernel and the agg2 fp32 round-trip (25.6MB).
// ---------------------------------------------------------------------------
__global__ __launch_bounds__(256) void gather_head_kernel(
    const unsigned short* __restrict__ tsrc, const int* __restrict__ offs,
    const unsigned* __restrict__ csr,
    const float* __restrict__ b2, const float* __restrict__ Wa,
    const float* __restrict__ ba, const float* __restrict__ Wp,
    const float* __restrict__ bp, float* __restrict__ out)
{
    const int node = blockIdx.x * 4 + (threadIdx.x >> 6);
    const int lane = (int)threadIdx.x & 63;
    const int half = lane >> 5;
    const int fl = lane & 31;
    if (node >= NNODES) return;
    const int beg = offs[node];
    const int end = offs[node + 1];
    float ax = 0.f, ay = 0.f;
    int i = beg;
    for (; i + 8 <= end; i += 8) {
        unsigned p[4], pk[4];
        #pragma unroll
        for (int k = 0; k < 4; ++k) p[k] = csr[i + 2 * k + half];
        #pragma unroll
        for (int k = 0; k < 4; ++k)
            pk[k] = *reinterpret_cast<const unsigned*>(
                tsrc + (size_t)(p[k] & 0xFFFFu) * HDIM + 2 * fl);
        #pragma unroll
        for (int k = 0; k < 4; ++k) {
            const float wgt = __uint_as_float(p[k] & 0xFFFF0000u);
            ax += wgt * bf2f((unsigned short)(pk[k] & 0xFFFFu));
            ay += wgt * bf2f((unsigned short)(pk[k] >> 16));
        }
    }
    for (; i + 2 <= end; i += 2) {
        const unsigned p = csr[i + half];
        const unsigned pk = *reinterpret_cast<const unsigned*>(
            tsrc + (size_t)(p & 0xFFFFu) * HDIM + 2 * fl);
        const float wgt = __uint_as_float(p & 0xFFFF0000u);
        ax += wgt * bf2f((unsigned short)(pk & 0xFFFFu));
        ay += wgt * bf2f((unsigned short)(pk >> 16));
    }
    if (i < end) {
        const unsigned p = csr[i];
        const unsigned pk = *reinterpret_cast<const unsigned*>(
            tsrc + (size_t)(p & 0xFFFFu) * HDIM + 2 * fl);
        const float wgt = (half == 0) ? __uint_as_float(p & 0xFFFF0000u) : 0.f;
        ax += wgt * bf2f((unsigned short)(pk & 0xFFFFu));
        ay += wgt * bf2f((unsigned short)(pk >> 16));
    }
    ax += __shfl_xor(ax, 32, 64);      // every lane now has full feature pair
    ay += __shfl_xor(ay, 32, 64);

    // head: per-lane partial dot over its feature pair
    const float2 bb = *reinterpret_cast<const float2*>(b2 + 2 * fl);
    const float2 wa = *reinterpret_cast<const float2*>(Wa + 2 * fl);
    const float2 wp = *reinterpret_cast<const float2*>(Wp + 2 * fl);
    const float h0 = fmaxf(ax + bb.x, 0.f);
    const float h1 = fmaxf(ay + bb.y, 0.f);
    float sa = h0 * wa.x + h1 * wa.y;
    float sp = h0 * wp.x + h1 * wp.y;
    // butterfly over xor 1..16: sums the 32 distinct feature pairs per half
    #pragma unroll
    for (int off = 1; off < 32; off <<= 1) {
        sa += __shfl_xor(sa, off, 64);
        sp += __shfl_xor(sp, off, 64);
    }
    if (lane == 0) {
        out[node] = sa + ba[0];
        out[NNODES + node] = sp + bp[0];
    }
}

// ---------------------------------------------------------------------------
// MFMA transform: t2 = relu(agg + b1) @ W2, bf16 out.
// Block = 64 nodes x 4 waves; A built in registers from coalesced loads.
// ---------------------------------------------------------------------------
__global__ __launch_bounds__(256) void transform_kernel(
    const float* __restrict__ agg, const float* __restrict__ bias,
    const float* __restrict__ W, unsigned short* __restrict__ out)
{
    const int lane = (int)threadIdx.x & 63;
    const int w = __builtin_amdgcn_readfirstlane((int)(threadIdx.x >> 6));
    const int col = lane & 15;
    const int quad = lane >> 4;
    const int node0 = (int)blockIdx.x * 64;
    const int jg = w * 16 + col;

    bf16x8 Bw0, Bw1;
    #pragma unroll
    for (int j = 0; j < 8; ++j) {
        Bw0[j] = (short)f2bf(W[(size_t)(quad * 8 + j) * HDIM + jg]);
        Bw1[j] = (short)f2bf(W[(size_t)(32 + quad * 8 + j) * HDIM + jg]);
    }
    float bk0[8], bk1[8];
    #pragma unroll
    for (int j = 0; j < 8; ++j) {
        bk0[j] = bias[quad * 8 + j];
        bk1[j] = bias[32 + quad * 8 + j];
    }

    #pragma unroll
    for (int mt = 0; mt < 4; ++mt) {
        int node = node0 + mt * 16 + col;
        if (node >= NNODES) node = 0;
        const float* arow = agg + (size_t)node * HDIM;
        bf16x8 a0, a1;
        #pragma unroll
        for (int j = 0; j < 8; ++j) {
            a0[j] = (short)f2bf(fmaxf(arow[quad * 8 + j] + bk0[j], 0.f));
            a1[j] = (short)f2bf(fmaxf(arow[32 + quad * 8 + j] + bk1[j], 0.f));
        }
        const f32x4 z4 = {0.f, 0.f, 0.f, 0.f};
        f32x4 aw;
        aw = __builtin_amdgcn_mfma_f32_16x16x32_bf16(a0, Bw0, z4, 0, 0, 0);
        aw = __builtin_amdgcn_mfma_f32_16x16x32_bf16(a1, Bw1, aw, 0, 0, 0);
        #pragma unroll
        for (int r = 0; r < 4; ++r) {
            const int nn = node0 + mt * 16 + quad * 4 + r;
            if (nn < NNODES) out[(size_t)nn * HDIM + jg] = f2bf(aw[r]);
        }
    }
}

extern "C" void kernel_launch(void* const* d_in, const int* in_sizes, int n_in,
                              void* d_out, int out_size, void* d_ws, size_t ws_size,
                              hipStream_t stream)
{
    const float* x_dyn  = (const float*)d_in[0];
    const float* x_stat = (const float*)d_in[1];
    const int*   eidx   = (const int*)  d_in[2];
    const float* ew     = (const float*)d_in[3];
    const float* Wih    = (const float*)d_in[4];
    const float* Whh    = (const float*)d_in[5];
    const float* bih    = (const float*)d_in[6];
    const float* bhh    = (const float*)d_in[7];
    const float* W1     = (const float*)d_in[8];
    const float* b1     = (const float*)d_in[9];
    const float* W2     = (const float*)d_in[10];
    const float* b2     = (const float*)d_in[11];
    const float* Wa     = (const float*)d_in[12];
    const float* ba     = (const float*)d_in[13];
    const float* Wp     = (const float*)d_in[14];
    const float* bp     = (const float*)d_in[15];

    const int* srcv = eidx;
    const int* dstv = eidx + NEDGES;

    // workspace layout (4B units)
    const size_t NH = (size_t)NNODES * HDIM;    // 3.2M elements
    float* ws   = (float*)d_ws;
    unsigned short* t1 = (unsigned short*)ws;                 // [NH] bf16
    unsigned short* t2 = (unsigned short*)(ws + NH / 2);      // [NH] bf16
    float* agg1 = ws + NH;            // [NH] fp32
    int*   deg    = (int*)(ws + 2 * NH);              // [NNODES]
    int*   offs   = deg + NNODES;                     // [NNODES+1]
    int*   cursor = offs + NNODES + 1;                // [NNODES]
    unsigned* csr = (unsigned*)(cursor + NNODES);     // [NEDGES] packed (src|w)

    dim3 blk(256);

    // ---- GRU + W1 (longest independent work first) ----
    gru_w1_kernel<<<dim3((NNODES + NB - 1) / NB), blk, 0, stream>>>(
        x_dyn, x_stat, Wih, Whh, bih, bhh, W1, t1);

    // ---- CSR build (once, reused by both layers) ----
    hipMemsetAsync(deg, 0, (size_t)NNODES * sizeof(int), stream);
    hist_kernel<<<dim3((NEDGES + 255) / 256), blk, 0, stream>>>(dstv, deg);
    scan_kernel<<<dim3(1), dim3(1024), 0, stream>>>(deg, offs, cursor);
    fill_kernel<<<dim3(((NEDGES + 255) / 256) * 8), blk, 0, stream>>>(
        srcv, dstv, ew, cursor, csr);

    // ---- layer 1 ----
    gather_kernel<<<dim3((NNODES + 3) / 4), blk, 0, stream>>>(t1, offs, csr, agg1);
    transform_kernel<<<dim3((NNODES + 63) / 64), blk, 0, stream>>>(agg1, b1, W2, t2);

    // ---- layer 2 (head fused into gather) ----
    gather_head_kernel<<<dim3((NNODES + 3) / 4), blk, 0, stream>>>(
        t2, offs, csr, b2, Wa, ba, Wp, bp, (float*)d_out);
}

// Round 12
// 385.158 us; speedup vs baseline: 1.6788x; 1.2822x over previous
//
#include <hip/hip_runtime.h>
#include <cstdint>
#include <cstddef>

#define NNODES 50000
#define TT 24
#define DYNF 16
#define STATF 8
#define HDIM 64
#define NEDGES 1600000
#define NB 32          // nodes per GRU block (16 regressed: VGPR cap -> spill)
#define GRU_BLOCKS ((NNODES + NB - 1) / NB)        // 1563
#define FILL_CHUNK 1024
#define FILL_CHUNKS ((NEDGES + FILL_CHUNK - 1) / FILL_CHUNK)  // 1563
#define CAP 128        // bucket capacity per node (avg deg 32; P(>=128) ~ 0)

typedef __attribute__((ext_vector_type(8))) short bf16x8;
typedef __attribute__((ext_vector_type(4))) float f32x4;

// fp32 -> bf16 with round-to-nearest-even
__device__ __forceinline__ unsigned short f2bf(float f) {
    unsigned u = __float_as_uint(f);
    u = (u + 0x7FFFu + ((u >> 16) & 1u)) >> 16;
    return (unsigned short)u;
}
__device__ __forceinline__ float bf2f(unsigned short s) {
    return __uint_as_float((unsigned)s << 16);
}
__device__ __forceinline__ bf16x8 cvt8(const float* __restrict__ p) {
    bf16x8 r;
    #pragma unroll
    for (int i = 0; i < 8; ++i) r[i] = (short)f2bf(p[i]);
    return r;
}
__device__ __forceinline__ bf16x8 zero8() {
    bf16x8 z;
    #pragma unroll
    for (int i = 0; i < 8; ++i) z[i] = 0;
    return z;
}
// robust fast tanh: no inf/inf NaN at extremes
__device__ __forceinline__ float fast_tanh(float x) {
    float e = __expf(2.f * x);
    return 1.f - 2.f * __builtin_amdgcn_rcpf(e + 1.f);
}

// ---------------------------------------------------------------------------
// Heterogeneous launch: blocks [0, GRU_BLOCKS) = MFMA GRU + fused W1
// (unchanged R10 body); blocks beyond = bucket-CSR fill (XCD dst-range
// partitioned). gru is VALU/MFMA-bound, fill is atomic/store-bound ->
// complementary pipes co-schedule (m114), hiding fill under gru.
// ---------------------------------------------------------------------------
__global__ __launch_bounds__(256, 4) void gru_fill_kernel(
    const float* __restrict__ x_dyn, const float* __restrict__ x_stat,
    const float* __restrict__ Wih, const float* __restrict__ Whh,
    const float* __restrict__ bih, const float* __restrict__ bhh,
    const float* __restrict__ W1, unsigned short* __restrict__ t1,
    const int* __restrict__ srcv, const int* __restrict__ dstv,
    const float* __restrict__ ew, int* __restrict__ cursor,
    unsigned* __restrict__ csr)
{
    constexpr int S_H = 72;   // bf16 units per hbuf row (144B: 16B-aligned)
    constexpr int S_X = 40;   // bf16 units per xbuf row
    __shared__ short hbuf[2][NB * S_H];   // [node][feature] bf16, dbuf
    __shared__ short xbuf[2][NB * S_X];   // [node][k] bf16; k 16..31 zeroed

    const int tid = (int)threadIdx.x;

    if ((int)blockIdx.x >= GRU_BLOCKS) {
        // ---------------- bucket-CSR fill ----------------
        const int fb = (int)blockIdx.x - GRU_BLOCKS;
        const int range = fb & 7;                  // XCD round-robin slice
        const int chunk = fb >> 3;
        const int base = chunk * FILL_CHUNK;
        const int lo = range * (NNODES / 8);
        const int hi = (range == 7) ? NNODES : lo + (NNODES / 8);
        #pragma unroll
        for (int j = 0; j < FILL_CHUNK / 256; ++j) {
            const int e = base + j * 256 + tid;
            if (e < NEDGES) {
                const int d = dstv[e];
                if (d >= lo && d < hi) {
                    const int pos = atomicAdd(&cursor[d], 1);
                    if (pos < CAP)
                        csr[(size_t)d * CAP + pos] =
                            (unsigned)srcv[e] | ((unsigned)f2bf(ew[e]) << 16);
                }
            }
        }
        return;
    }

    // ---------------- GRU + W1 (unchanged) ----------------
    const int lane = tid & 63;
    const int w = __builtin_amdgcn_readfirstlane(tid >> 6);  // wave 0..3
    const int col = lane & 15;
    const int quad = lane >> 4;
    const int node0 = (int)blockIdx.x * NB;

    bf16x8 Bh[3][2];
    bf16x8 Bx[3];
    #pragma unroll
    for (int g = 0; g < 3; ++g) {
        const int n = (w + g * 4) * 16 + col;   // gate row in [0,192)
        #pragma unroll
        for (int kt = 0; kt < 2; ++kt)
            Bh[g][kt] = cvt8(Whh + (size_t)n * HDIM + kt * 32 + quad * 8);
        Bx[g] = (quad < 2) ? cvt8(Wih + (size_t)n * DYNF + quad * 8) : zero8();
    }

    const int jg = w * 16 + col;                 // feature 0..63
    const float b_r  = bih[jg]        + bhh[jg];
    const float b_z  = bih[HDIM + jg] + bhh[HDIM + jg];
    const float b_xn = bih[2 * HDIM + jg];
    const float b_hn = bhh[2 * HDIM + jg];

    for (int i = tid; i < NB * S_H; i += 256) hbuf[0][i] = 0;

    auto stage_x = [&](int t, int b) {
        const int nd = tid >> 3, c = tid & 7;
        int node = node0 + nd;
        if (node >= NNODES) node = 0;
        const float2 v = *reinterpret_cast<const float2*>(
            x_dyn + (size_t)node * (TT * DYNF) + t * DYNF + c * 2);
        unsigned pk = (unsigned)f2bf(v.x) | ((unsigned)f2bf(v.y) << 16);
        *reinterpret_cast<unsigned*>(&xbuf[b][nd * S_X + c * 2]) = pk;
        *reinterpret_cast<unsigned*>(&xbuf[b][nd * S_X + 16 + c * 2]) = 0u;
    };
    stage_x(0, 0);

    float hprev[2][4];
    #pragma unroll
    for (int mt = 0; mt < 2; ++mt)
        #pragma unroll
        for (int r = 0; r < 4; ++r) hprev[mt][r] = 0.f;

    for (int t = 0; t < TT; ++t) {
        const int rb = t & 1;
        __syncthreads();   // hbuf[rb], xbuf[rb] ready

        f32x4 accr[2], accz[2], accnh[2], accnx[2];
        #pragma unroll
        for (int mt = 0; mt < 2; ++mt) {
            const int nd = mt * 16 + col;   // A-frag: m = lane&15 within tile
            const bf16x8 a0 = *reinterpret_cast<const bf16x8*>(&hbuf[rb][nd * S_H + quad * 8]);
            const bf16x8 a1 = *reinterpret_cast<const bf16x8*>(&hbuf[rb][nd * S_H + 32 + quad * 8]);
            const bf16x8 ax = *reinterpret_cast<const bf16x8*>(&xbuf[rb][nd * S_X + quad * 8]);
            const f32x4 z4 = {0.f, 0.f, 0.f, 0.f};
            accr[mt]  = __builtin_amdgcn_mfma_f32_16x16x32_bf16(a0, Bh[0][0], z4, 0, 0, 0);
            accr[mt]  = __builtin_amdgcn_mfma_f32_16x16x32_bf16(a1, Bh[0][1], accr[mt], 0, 0, 0);
            accr[mt]  = __builtin_amdgcn_mfma_f32_16x16x32_bf16(ax, Bx[0],    accr[mt], 0, 0, 0);
            accz[mt]  = __builtin_amdgcn_mfma_f32_16x16x32_bf16(a0, Bh[1][0], z4, 0, 0, 0);
            accz[mt]  = __builtin_amdgcn_mfma_f32_16x16x32_bf16(a1, Bh[1][1], accz[mt], 0, 0, 0);
            accz[mt]  = __builtin_amdgcn_mfma_f32_16x16x32_bf16(ax, Bx[1],    accz[mt], 0, 0, 0);
            accnh[mt] = __builtin_amdgcn_mfma_f32_16x16x32_bf16(a0, Bh[2][0], z4, 0, 0, 0);
            accnh[mt] = __builtin_amdgcn_mfma_f32_16x16x32_bf16(a1, Bh[2][1], accnh[mt], 0, 0, 0);
            accnx[mt] = __builtin_amdgcn_mfma_f32_16x16x32_bf16(ax, Bx[2],    z4, 0, 0, 0);
        }

        if (t + 1 < TT) stage_x(t + 1, rb ^ 1);  // overlap with MFMA drain

        #pragma unroll
        for (int mt = 0; mt < 2; ++mt) {
            #pragma unroll
            for (int r = 0; r < 4; ++r) {
                const float dr = 1.f + __expf(-(accr[mt][r] + b_r));
                const float dz = 1.f + __expf(-(accz[mt][r] + b_z));
                const float q  = __builtin_amdgcn_rcpf(dr * dz);
                const float R  = q * dz;           // = 1/dr
                const float Z  = q * dr;           // = 1/dz
                const float Nn = fast_tanh(accnx[mt][r] + b_xn + R * (accnh[mt][r] + b_hn));
                const float hn = Nn + Z * (hprev[mt][r] - Nn);
                hprev[mt][r] = hn;
                hbuf[rb ^ 1][(mt * 16 + quad * 4 + r) * S_H + jg] = (short)f2bf(hn);
            }
        }
    }
    __syncthreads();   // final h in hbuf[0]

    // ---- fused W1: t1 = [h | x_stat] @ W1 (bf16 out) ----
    bf16x8 Bw0, Bw1, Bw2;
    #pragma unroll
    for (int j = 0; j < 8; ++j) {
        Bw0[j] = (short)f2bf(W1[(size_t)(quad * 8 + j) * HDIM + jg]);
        Bw1[j] = (short)f2bf(W1[(size_t)(32 + quad * 8 + j) * HDIM + jg]);
    }
    if (quad == 0) {
        #pragma unroll
        for (int j = 0; j < 8; ++j)
            Bw2[j] = (short)f2bf(W1[(size_t)(HDIM + j) * HDIM + jg]);
    } else {
        Bw2 = zero8();
    }

    #pragma unroll
    for (int mt = 0; mt < 2; ++mt) {
        const int nd = mt * 16 + col;
        const bf16x8 a0 = *reinterpret_cast<const bf16x8*>(&hbuf[0][nd * S_H + quad * 8]);
        const bf16x8 a1 = *reinterpret_cast<const bf16x8*>(&hbuf[0][nd * S_H + 32 + quad * 8]);
        bf16x8 axs;
        if (quad == 0) {
            int node = node0 + nd;
            if (node >= NNODES) node = 0;
            axs = cvt8(x_stat + (size_t)node * STATF);
        } else {
            axs = zero8();
        }
        const f32x4 z4 = {0.f, 0.f, 0.f, 0.f};
        f32x4 aw;
        aw = __builtin_amdgcn_mfma_f32_16x16x32_bf16(a0, Bw0, z4, 0, 0, 0);
        aw = __builtin_amdgcn_mfma_f32_16x16x32_bf16(a1, Bw1, aw, 0, 0, 0);
        aw = __builtin_amdgcn_mfma_f32_16x16x32_bf16(axs, Bw2, aw, 0, 0, 0);
        #pragma unroll
        for (int r = 0; r < 4; ++r) {
            const int node = node0 + mt * 16 + quad * 4 + r;
            if (node < NNODES) t1[(size_t)node * HDIM + jg] = f2bf(aw[r]);
        }
    }
}

// ---------------------------------------------------------------------------
// Gather-reduce, 2 edges per wave (bucket CSR: base node*CAP, count=cursor).
// ---------------------------------------------------------------------------
__global__ __launch_bounds__(256) void gather_kernel(
    const unsigned short* __restrict__ tsrc, const int* __restrict__ cursor,
    const unsigned* __restrict__ csr, float* __restrict__ agg)
{
    const int node = blockIdx.x * 4 + (threadIdx.x >> 6);
    const int lane = (int)threadIdx.x & 63;
    const int half = lane >> 5;
    const int fl = lane & 31;          // feature pair (2*fl, 2*fl+1)
    if (node >= NNODES) return;
    const int beg = node * CAP;
    const int cnt = min(cursor[node], CAP);
    const int end = beg + cnt;
    float ax = 0.f, ay = 0.f;
    int i = beg;
    for (; i + 8 <= end; i += 8) {     // 4 row-requests in flight per half
        unsigned p[4], pk[4];
        #pragma unroll
        for (int k = 0; k < 4; ++k) p[k] = csr[i + 2 * k + half];
        #pragma unroll
        for (int k = 0; k < 4; ++k)
            pk[k] = *reinterpret_cast<const unsigned*>(
                tsrc + (size_t)(p[k] & 0xFFFFu) * HDIM + 2 * fl);
        #pragma unroll
        for (int k = 0; k < 4; ++k) {
            const float wgt = __uint_as_float(p[k] & 0xFFFF0000u);
            ax += wgt * bf2f((unsigned short)(pk[k] & 0xFFFFu));
            ay += wgt * bf2f((unsigned short)(pk[k] >> 16));
        }
    }
    for (; i + 2 <= end; i += 2) {
        const unsigned p = csr[i + half];
        const unsigned pk = *reinterpret_cast<const unsigned*>(
            tsrc + (size_t)(p & 0xFFFFu) * HDIM + 2 * fl);
        const float wgt = __uint_as_float(p & 0xFFFF0000u);
        ax += wgt * bf2f((unsigned short)(pk & 0xFFFFu));
        ay += wgt * bf2f((unsigned short)(pk >> 16));
    }
    if (i < end) {                     // single leftover: half 0 contributes
        const unsigned p = csr[i];
        const unsigned pk = *reinterpret_cast<const unsigned*>(
            tsrc + (size_t)(p & 0xFFFFu) * HDIM + 2 * fl);
        const float wgt = (half == 0) ? __uint_as_float(p & 0xFFFF0000u) : 0.f;
        ax += wgt * bf2f((unsigned short)(pk & 0xFFFFu));
        ay += wgt * bf2f((unsigned short)(pk >> 16));
    }
    ax += __shfl_xor(ax, 32, 64);      // combine halves
    ay += __shfl_xor(ay, 32, 64);
    if (half == 0) {
        float2 o; o.x = ax; o.y = ay;
        *reinterpret_cast<float2*>(agg + (size_t)node * HDIM + 2 * fl) = o;
    }
}

// ---------------------------------------------------------------------------
// Gather + fused head for layer 2 (bucket CSR).
// ---------------------------------------------------------------------------
__global__ __launch_bounds__(256) void gather_head_kernel(
    const unsigned short* __restrict__ tsrc, const int* __restrict__ cursor,
    const unsigned* __restrict__ csr,
    const float* __restrict__ b2, const float* __restrict__ Wa,
    const float* __restrict__ ba, const float* __restrict__ Wp,
    const float* __restrict__ bp, float* __restrict__ out)
{
    const int node = blockIdx.x * 4 + (threadIdx.x >> 6);
    const int lane = (int)threadIdx.x & 63;
    const int half = lane >> 5;
    const int fl = lane & 31;
    if (node >= NNODES) return;
    const int beg = node * CAP;
    const int cnt = min(cursor[node], CAP);
    const int end = beg + cnt;
    float ax = 0.f, ay = 0.f;
    int i = beg;
    for (; i + 8 <= end; i += 8) {
        unsigned p[4], pk[4];
        #pragma unroll
        for (int k = 0; k < 4; ++k) p[k] = csr[i + 2 * k + half];
        #pragma unroll
        for (int k = 0; k < 4; ++k)
            pk[k] = *reinterpret_cast<const unsigned*>(
                tsrc + (size_t)(p[k] & 0xFFFFu) * HDIM + 2 * fl);
        #pragma unroll
        for (int k = 0; k < 4; ++k) {
            const float wgt = __uint_as_float(p[k] & 0xFFFF0000u);
            ax += wgt * bf2f((unsigned short)(pk[k] & 0xFFFFu));
            ay += wgt * bf2f((unsigned short)(pk[k] >> 16));
        }
    }
    for (; i + 2 <= end; i += 2) {
        const unsigned p = csr[i + half];
        const unsigned pk = *reinterpret_cast<const unsigned*>(
            tsrc + (size_t)(p & 0xFFFFu) * HDIM + 2 * fl);
        const float wgt = __uint_as_float(p & 0xFFFF0000u);
        ax += wgt * bf2f((unsigned short)(pk & 0xFFFFu));
        ay += wgt * bf2f((unsigned short)(pk >> 16));
    }
    if (i < end) {
        const unsigned p = csr[i];
        const unsigned pk = *reinterpret_cast<const unsigned*>(
            tsrc + (size_t)(p & 0xFFFFu) * HDIM + 2 * fl);
        const float wgt = (half == 0) ? __uint_as_float(p & 0xFFFF0000u) : 0.f;
        ax += wgt * bf2f((unsigned short)(pk & 0xFFFFu));
        ay += wgt * bf2f((unsigned short)(pk >> 16));
    }
    ax += __shfl_xor(ax, 32, 64);      // every lane now has its feature pair
    ay += __shfl_xor(ay, 32, 64);

    const float2 bb = *reinterpret_cast<const float2*>(b2 + 2 * fl);
    const float2 wa = *reinterpret_cast<const float2*>(Wa + 2 * fl);
    const float2 wp = *reinterpret_cast<const float2*>(Wp + 2 * fl);
    const float h0 = fmaxf(ax + bb.x, 0.f);
    const float h1 = fmaxf(ay + bb.y, 0.f);
    float sa = h0 * wa.x + h1 * wa.y;
    float sp = h0 * wp.x + h1 * wp.y;
    #pragma unroll
    for (int off = 1; off < 32; off <<= 1) {
        sa += __shfl_xor(sa, off, 64);
        sp += __shfl_xor(sp, off, 64);
    }
    if (lane == 0) {
        out[node] = sa + ba[0];
        out[NNODES + node] = sp + bp[0];
    }
}

// ---------------------------------------------------------------------------
// MFMA transform: t2 = relu(agg + b1) @ W2, bf16 out.
// ---------------------------------------------------------------------------
__global__ __launch_bounds__(256) void transform_kernel(
    const float* __restrict__ agg, const float* __restrict__ bias,
    const float* __restrict__ W, unsigned short* __restrict__ out)
{
    const int lane = (int)threadIdx.x & 63;
    const int w = __builtin_amdgcn_readfirstlane((int)(threadIdx.x >> 6));
    const int col = lane & 15;
    const int quad = lane >> 4;
    const int node0 = (int)blockIdx.x * 64;
    const int jg = w * 16 + col;

    bf16x8 Bw0, Bw1;
    #pragma unroll
    for (int j = 0; j < 8; ++j) {
        Bw0[j] = (short)f2bf(W[(size_t)(quad * 8 + j) * HDIM + jg]);
        Bw1[j] = (short)f2bf(W[(size_t)(32 + quad * 8 + j) * HDIM + jg]);
    }
    float bk0[8], bk1[8];
    #pragma unroll
    for (int j = 0; j < 8; ++j) {
        bk0[j] = bias[quad * 8 + j];
        bk1[j] = bias[32 + quad * 8 + j];
    }

    #pragma unroll
    for (int mt = 0; mt < 4; ++mt) {
        int node = node0 + mt * 16 + col;
        if (node >= NNODES) node = 0;
        const float* arow = agg + (size_t)node * HDIM;
        bf16x8 a0, a1;
        #pragma unroll
        for (int j = 0; j < 8; ++j) {
            a0[j] = (short)f2bf(fmaxf(arow[quad * 8 + j] + bk0[j], 0.f));
            a1[j] = (short)f2bf(fmaxf(arow[32 + quad * 8 + j] + bk1[j], 0.f));
        }
        const f32x4 z4 = {0.f, 0.f, 0.f, 0.f};
        f32x4 aw;
        aw = __builtin_amdgcn_mfma_f32_16x16x32_bf16(a0, Bw0, z4, 0, 0, 0);
        aw = __builtin_amdgcn_mfma_f32_16x16x32_bf16(a1, Bw1, aw, 0, 0, 0);
        #pragma unroll
        for (int r = 0; r < 4; ++r) {
            const int nn = node0 + mt * 16 + quad * 4 + r;
            if (nn < NNODES) out[(size_t)nn * HDIM + jg] = f2bf(aw[r]);
        }
    }
}

extern "C" void kernel_launch(void* const* d_in, const int* in_sizes, int n_in,
                              void* d_out, int out_size, void* d_ws, size_t ws_size,
                              hipStream_t stream)
{
    const float* x_dyn  = (const float*)d_in[0];
    const float* x_stat = (const float*)d_in[1];
    const int*   eidx   = (const int*)  d_in[2];
    const float* ew     = (const float*)d_in[3];
    const float* Wih    = (const float*)d_in[4];
    const float* Whh    = (const float*)d_in[5];
    const float* bih    = (const float*)d_in[6];
    const float* bhh    = (const float*)d_in[7];
    const float* W1     = (const float*)d_in[8];
    const float* b1     = (const float*)d_in[9];
    const float* W2     = (const float*)d_in[10];
    const float* b2     = (const float*)d_in[11];
    const float* Wa     = (const float*)d_in[12];
    const float* ba     = (const float*)d_in[13];
    const float* Wp     = (const float*)d_in[14];
    const float* bp     = (const float*)d_in[15];

    const int* srcv = eidx;
    const int* dstv = eidx + NEDGES;

    // workspace layout (4B units)
    const size_t NH = (size_t)NNODES * HDIM;    // 3.2M elements
    float* ws   = (float*)d_ws;
    unsigned short* t1 = (unsigned short*)ws;                 // [NH] bf16
    unsigned short* t2 = (unsigned short*)(ws + NH / 2);      // [NH] bf16
    float* agg1 = ws + NH;            // [NH] fp32
    unsigned* csr = (unsigned*)(ws + 2 * NH);         // [NNODES*CAP] packed
    int* cursor = (int*)(csr + (size_t)NNODES * CAP); // [NNODES]

    dim3 blk(256);

    // cursor must be zero before the combined launch
    hipMemsetAsync(cursor, 0, (size_t)NNODES * sizeof(int), stream);

    // ---- GRU + W1 co-scheduled with bucket-CSR fill ----
    gru_fill_kernel<<<dim3(GRU_BLOCKS + FILL_CHUNKS * 8), blk, 0, stream>>>(
        x_dyn, x_stat, Wih, Whh, bih, bhh, W1, t1,
        srcv, dstv, ew, cursor, csr);

    // ---- layer 1 ----
    gather_kernel<<<dim3((NNODES + 3) / 4), blk, 0, stream>>>(t1, cursor, csr, agg1);
    transform_kernel<<<dim3((NNODES + 63) / 64), blk, 0, stream>>>(agg1, b1, W2, t2);

    // ---- layer 2 (head fused into gather) ----
    gather_head_kernel<<<dim3((NNODES + 3) / 4), blk, 0, stream>>>(
        t2, cursor, csr, b2, Wa, ba, Wp, bp, (float*)d_out);
}